// Round 1
// baseline (325.961 us; speedup 1.0000x reference)
//
#include <hip/hip_runtime.h>
#include <hip/hip_bf16.h>
#include <math.h>

constexpr int kBS = 2;
constexpr int kNQ = 20197;
constexpr int kNV = 20197;
constexpr int kM  = kBS * kNQ;   // 40394
constexpr int kMT = 632;         // 64-row m-tiles (40448 rows incl. slack)
constexpr int kMpad = kMT * 64;  // 40448

__constant__ int cLH[4] = {100, 50, 25, 13};
__constant__ int cLW[4] = {152, 76, 38, 19};
__constant__ int cLS[4] = {0, 15200, 19000, 19950};

typedef __bf16 bf16x8 __attribute__((ext_vector_type(8)));
typedef float  f32x4  __attribute__((ext_vector_type(4)));
typedef float  f32x2  __attribute__((ext_vector_type(2)));

__device__ __forceinline__ unsigned short f2bf(float x) {
    unsigned u = __float_as_uint(x);
    return (unsigned short)((u + 0x7fffu + ((u >> 16) & 1u)) >> 16);
}
__device__ __forceinline__ unsigned pack2(float a, float b) {
    return (unsigned)f2bf(a) | ((unsigned)f2bf(b) << 16);
}
__device__ __forceinline__ float bflo(unsigned u) { return __uint_as_float(u << 16); }
__device__ __forceinline__ float bfhi(unsigned u) { return __uint_as_float(u & 0xffff0000u); }
__device__ __forceinline__ void gload_lds16(const void* g, void* s) {
    __builtin_amdgcn_global_load_lds(
        (const __attribute__((address_space(1))) void*)g,
        (__attribute__((address_space(3))) void*)s, 16, 0, 0);
}
__device__ __forceinline__ void vmwait(int n) {
    if (n == 0)      asm volatile("s_waitcnt vmcnt(0)" ::: "memory");
    else if (n == 2) asm volatile("s_waitcnt vmcnt(2)" ::: "memory");
    else             asm volatile("s_waitcnt vmcnt(4)" ::: "memory");
}

// ---------------------------------------------------------------------------
// prep_w: weight transposes (fp32 KxN -> bf16 NxK) + fused bias384.
// Coalesced READS, scattered 2B writes (fire-and-forget).
// ---------------------------------------------------------------------------
__global__ __launch_bounds__(256) void prep_w(
    const float* __restrict__ Wv, const float* __restrict__ Wso,
    const float* __restrict__ Waw, const float* __restrict__ Wo,
    const float* __restrict__ bso, const float* __restrict__ baw,
    unsigned short* __restrict__ WvT, unsigned short* __restrict__ WsoawT,
    unsigned short* __restrict__ WoT, float* __restrict__ bias384)
{
    int k = blockIdx.x * 256 + threadIdx.x;
    if (k < 65536) { int kk = k >> 8, n = k & 255; WvT[n * 256 + kk] = f2bf(Wv[k]); return; }
    k -= 65536;
    if (k < 65536) { int kk = k >> 8, n = k & 255; WsoawT[n * 256 + kk] = f2bf(Wso[k]); return; }
    k -= 65536;
    if (k < 32768) { int kk = k >> 7, n = k & 127; WsoawT[(256 + n) * 256 + kk] = f2bf(Waw[k]); return; }
    k -= 32768;
    if (k < 65536) { int kk = k >> 8, n = k & 255; WoT[n * 256 + kk] = f2bf(Wo[k]); return; }
    k -= 65536;
    if (k < 384) bias384[k] = (k < 256) ? bso[k] : baw[k - 256];
}

// ---------------------------------------------------------------------------
// Panel GEMM core: C[64, N] = A_tile[64, 256] @ BT[N, 256]^T + bias (+res).
// A staged once into LDS (XOR slot-swizzle, linear pitch 256).
// B: 4-deep rotating 8KB panels via global_load_lds, raw s_barrier +
// counted vmcnt (2 panels always in flight). XOR-swizzled B layout
// (pre-swizzled global source, matching swizzled ds_read) -> conflict-free.
// 256 thr, 4 waves (2x2 over 32x64 outputs each), mfma 16x16x32, acc 2x4.
// ---------------------------------------------------------------------------
template<int AFP32, int CFP32>
__device__ __forceinline__ void gemm_core(
    const void* __restrict__ Av, const __hip_bfloat16* __restrict__ BT,
    const float* __restrict__ bias, const float* __restrict__ res,
    int N, int NT, void* __restrict__ Cv, int m0)
{
    __shared__ __hip_bfloat16 As[64 * 256];      // 32 KB
    __shared__ __hip_bfloat16 Bs[4][128 * 32];   // 4 x 8 KB rotating

    const int t = threadIdx.x;
    const int wave = t >> 6, lane = t & 63;
    const int quad = lane >> 4, l16 = lane & 15;
    const int mw = (wave & 1) * 32, nw = (wave >> 1) * 64;
    const int NCH = NT * 8;

    // panel g: n-tile g>>3, k-chunk g&7, buffer g&3.
    // physical 16B slot s = row*4 + qp; logical K-block ql = qp ^ ((row>>1)&3)
    auto issueB = [&](int g) {
        const int nti = g >> 3, kc = g & 7, buf = g & 3;
        #pragma unroll
        for (int j = 0; j < 2; ++j) {
            int s = j * 256 + t;
            int row = s >> 2;
            int ql = (s & 3) ^ ((row >> 1) & 3);
            gload_lds16((const char*)BT + (size_t)(nti * 128 + row) * 512
                            + kc * 64 + ql * 16,
                        (char*)&Bs[buf][0] + s * 16);
        }
    };

    if (AFP32) {
        const float* af = (const float*)Av;
        float4 fr[16];
        #pragma unroll
        for (int p = 0; p < 16; ++p) {          // A loads FIRST (vmcnt hygiene)
            int idx = p * 256 + t;
            int row = idx >> 6, col4 = idx & 63;
            fr[p] = make_float4(0.f, 0.f, 0.f, 0.f);
            if (m0 + row < kM)
                fr[p] = *(const float4*)(af + (size_t)(m0 + row) * 256 + col4 * 4);
        }
        issueB(0); issueB(1); issueB(2);        // B prefetch rides under convert
        #pragma unroll
        for (int p = 0; p < 16; ++p) {
            int idx = p * 256 + t;
            int row = idx >> 6, col4 = idx & 63;
            int ps = (col4 >> 1) ^ (row & 7);   // 16B-slot XOR swizzle
            uint2 u = make_uint2(pack2(fr[p].x, fr[p].y), pack2(fr[p].z, fr[p].w));
            *(uint2*)(void*)((char*)As + row * 512 + ps * 16 + (col4 & 1) * 8) = u;
        }
        asm volatile("s_waitcnt lgkmcnt(0)" ::: "memory");  // ds_writes drained pre-barrier
    } else {
        const unsigned short* ab = (const unsigned short*)Av;  // kMpad rows: no guard
        #pragma unroll
        for (int p = 0; p < 8; ++p) {            // direct DMA, pre-swizzled source
            int s = p * 256 + t;
            int row = s >> 5;
            int slog = (s & 31) ^ (row & 7);
            gload_lds16(ab + (size_t)(m0 + row) * 256 + slog * 8,
                        (char*)As + s * 16);
        }
        issueB(0); issueB(1); issueB(2);
    }

    for (int nti = 0; nti < NT; ++nti) {
        f32x4 acc[2][4] = {};
        #pragma unroll
        for (int kc = 0; kc < 8; ++kc) {
            const int g = nti * 8 + kc;
            const int left = NCH - 1 - g;
            vmwait(left >= 2 ? 4 : 2 * left);    // panel g landed; g+1,g+2 in flight
            asm volatile("s_barrier" ::: "memory");
            if (g + 3 < NCH) issueB(g + 3);      // keep 3 panels in flight

            const int buf = g & 3;
            bf16x8 afr[2], bfr[4];
            #pragma unroll
            for (int mt = 0; mt < 2; ++mt) {
                int row = mw + mt * 16 + l16;
                int ps = (kc * 4 + quad) ^ (row & 7);
                afr[mt] = *(const bf16x8*)(const void*)
                    ((const char*)As + row * 512 + ps * 16);
            }
            #pragma unroll
            for (int nt = 0; nt < 4; ++nt) {
                int r = nw + nt * 16 + l16;
                int qp = quad ^ ((r >> 1) & 3);
                bfr[nt] = *(const bf16x8*)(const void*)
                    ((const char*)&Bs[buf][0] + r * 64 + qp * 16);
            }
            #pragma unroll
            for (int mt = 0; mt < 2; ++mt)
                #pragma unroll
                for (int nt = 0; nt < 4; ++nt)
                    acc[mt][nt] = __builtin_amdgcn_mfma_f32_16x16x32_bf16(
                        afr[mt], bfr[nt], acc[mt][nt], 0, 0, 0);
        }
        // epilogue for this n-tile (C/D: col=lane&15, row=quad*4+reg)
        const int n0g = nti * 128;
        #pragma unroll
        for (int nt = 0; nt < 4; ++nt) {
            int col = n0g + nw + nt * 16 + l16;
            float bvv = bias[col];
            #pragma unroll
            for (int mt = 0; mt < 2; ++mt) {
                #pragma unroll
                for (int i = 0; i < 4; ++i) {
                    int row = m0 + mw + mt * 16 + quad * 4 + i;
                    if (row < kM) {
                        float val = acc[mt][nt][i] + bvv;
                        if (CFP32)
                            ((float*)Cv)[(size_t)row * N + col] =
                                val + res[(size_t)row * N + col];
                        else
                            ((unsigned short*)Cv)[(size_t)row * N + col] = f2bf(val);
                    }
                }
            }
        }
    }
}

// bx=0: v_b = value @ WvT^T + bv; bx=1: soaw = query @ WsoawT^T + bias384
__global__ __launch_bounds__(256, 2) void gemm_dual(
    const float* __restrict__ value, const __hip_bfloat16* __restrict__ WvT,
    const float* __restrict__ bv, unsigned short* __restrict__ v_b,
    const float* __restrict__ query, const __hip_bfloat16* __restrict__ WsoawT,
    const float* __restrict__ b384, unsigned short* __restrict__ soaw)
{
    const int m0 = blockIdx.y * 64;
    const float* A; const __hip_bfloat16* BT; const float* bias;
    unsigned short* C; int N, NT;
    if (blockIdx.x == 0) { A = value; BT = WvT;    bias = bv;   C = v_b;  N = 256; NT = 2; }
    else                 { A = query; BT = WsoawT; bias = b384; C = soaw; N = 384; NT = 3; }
    gemm_core<1, 0>(A, BT, bias, nullptr, N, NT, C, m0);
}

// out = mid_b(bf16) @ WoT^T + bo + query (fp32 out)
__global__ __launch_bounds__(256, 2) void gemm_final(
    const unsigned short* __restrict__ mid_b, const __hip_bfloat16* __restrict__ WoT,
    const float* __restrict__ bo, const float* __restrict__ query,
    float* __restrict__ out)
{
    gemm_core<0, 1>(mid_b, WoT, bo, query, 256, 2, out, blockIdx.y * 64);
}

// ---------------------------------------------------------------------------
// Sampler: 1 block (128 thr) per query. Phase 1 unchanged math; stores
// (byte_off, weight) interleaved as int2 -> single ds_read_b64 in phase 2.
// Phase 2: uniform-base saddr loads (1 v_add), packed f32x2 FMA.
// ---------------------------------------------------------------------------
__global__ __launch_bounds__(128) void msda_sample(
    const __hip_bfloat16* __restrict__ v,     // (BS*NV, 256) bf16
    const __hip_bfloat16* __restrict__ soaw,  // (M, 384) bf16: so | logits
    const float* __restrict__ rp,             // (M, 4, 2)
    __hip_bfloat16* __restrict__ mid)         // (kMpad, 256) bf16
{
    const int bq = blockIdx.x;
    const int b  = bq >= kNQ;
    const int t  = threadIdx.x;

    __shared__ int2 sP[128 * 5];   // 5120 B: (byte_off, weight) x4 + pad

    {   // phase 1
        const int h = t >> 4, lp = t & 15, l = lp >> 2;
        unsigned sopk = *(const unsigned*)(const void*)(soaw + (size_t)bq * 384 + 2 * t);
        float logit = bflo((unsigned)*(const unsigned short*)(const void*)
                           (soaw + (size_t)bq * 384 + 256 + t));
        float2 rr = *(const float2*)(rp + (size_t)bq * 8 + l * 2);
        float sx = bflo(sopk), sy = bfhi(sopk);

        float mx = logit;
        #pragma unroll
        for (int s = 8; s >= 1; s >>= 1) mx = fmaxf(mx, __shfl_xor(mx, s, 16));
        float e = __expf(logit - mx);
        float sum = e;
        #pragma unroll
        for (int s = 8; s >= 1; s >>= 1) sum += __shfl_xor(sum, s, 16);
        float w = e / sum;

        const int ww = cLW[l], hh = cLH[l];
        const float fw = (float)ww, fh = (float)hh;
        float x = rr.x * fw + sx - 0.5f;
        float y = rr.y * fh + sy - 0.5f;
        float xf = floorf(x), yf = floorf(y);
        int x0 = (int)xf, y0 = (int)yf;
        float wx1 = x - xf, wx0 = 1.f - wx1;
        float wy1 = y - yf, wy0 = 1.f - wy1;
        bool vx0 = (x0 >= 0) & (x0 < ww);
        bool vx1 = (x0 >= -1) & (x0 + 1 < ww);
        bool vy0 = (y0 >= 0) & (y0 < hh);
        bool vy1 = (y0 >= -1) & (y0 + 1 < hh);
        int cx0 = min(max(x0, 0), ww - 1);
        int cx1 = min(max(x0 + 1, 0), ww - 1);
        int cy0 = min(max(y0, 0), hh - 1);
        int cy1 = min(max(y0 + 1, 0), hh - 1);
        const int base2 = cLS[l] * 512 + h * 64;             // BYTE offsets
        sP[t * 5 + 0] = make_int2(base2 + (cy0 * ww + cx0) * 512,
                                  __float_as_int((vx0 & vy0) ? w * wx0 * wy0 : 0.f));
        sP[t * 5 + 1] = make_int2(base2 + (cy0 * ww + cx1) * 512,
                                  __float_as_int((vx1 & vy0) ? w * wx1 * wy0 : 0.f));
        sP[t * 5 + 2] = make_int2(base2 + (cy1 * ww + cx0) * 512,
                                  __float_as_int((vx0 & vy1) ? w * wx0 * wy1 : 0.f));
        sP[t * 5 + 3] = make_int2(base2 + (cy1 * ww + cx1) * 512,
                                  __float_as_int((vx1 & vy1) ? w * wx1 * wy1 : 0.f));
    }
    __syncthreads();

    // phase 2
    const int h = t >> 4, c = (t & 15) * 2;
    const char* vb = (const char*)v + (size_t)b * ((size_t)kNV * 512);  // uniform base
    const unsigned cb = (unsigned)(c * 2);
    f32x2 acc = {0.f, 0.f};
    const int p0 = h * 16;
    #pragma unroll 8
    for (int pp = 0; pp < 16; ++pp) {
        const int idx = (p0 + pp) * 5;
        #pragma unroll
        for (int k2 = 0; k2 < 4; ++k2) {
            int2 pw = sP[idx + k2];
            float wgt = __int_as_float(pw.y);
            unsigned u = *(const unsigned*)(const void*)(vb + ((unsigned)pw.x + cb));
            f32x2 xy; xy.x = bflo(u); xy.y = bfhi(u);
            f32x2 w2; w2.x = wgt; w2.y = wgt;
            acc = xy * w2 + acc;          // ffp-contract -> v_pk_fma_f32
        }
    }
    *(unsigned*)(void*)(mid + (size_t)bq * 256 + h * 32 + c) = pack2(acc.x, acc.y);
}

// ---------------------------------------------------------------------------
extern "C" void kernel_launch(void* const* d_in, const int* in_sizes, int n_in,
                              void* d_out, int out_size, void* d_ws, size_t ws_size,
                              hipStream_t stream)
{
    const float* query = (const float*)d_in[0];
    const float* value = (const float*)d_in[1];
    const float* rp    = (const float*)d_in[2];
    const float* Wv  = (const float*)d_in[5];
    const float* bv  = (const float*)d_in[6];
    const float* Wso = (const float*)d_in[7];
    const float* bso = (const float*)d_in[8];
    const float* Waw = (const float*)d_in[9];
    const float* baw = (const float*)d_in[10];
    const float* Wo  = (const float*)d_in[11];
    const float* bo  = (const float*)d_in[12];

    // d_out overlay: v_b bf16 (kM*512 B) in first half; dead before the
    // final GEMM rewrites all of d_out.
    unsigned short* v_b = (unsigned short*)d_out;

    // ws: soaw bf16 (kM*384) | mid_b bf16 (kMpad*256) | WvT | WsoawT | WoT | bias384
    char* p = (char*)d_ws;
    __hip_bfloat16* soaw  = (__hip_bfloat16*)p;  p += (size_t)kM * 384 * 2;
    unsigned short* mid_b = (unsigned short*)p;  p += (size_t)kMpad * 256 * 2;
    unsigned short* WvT    = (unsigned short*)p; p += 256 * 256 * 2;
    unsigned short* WsoawT = (unsigned short*)p; p += 384 * 256 * 2;
    unsigned short* WoT    = (unsigned short*)p; p += 256 * 256 * 2;
    float* bias384         = (float*)p;

    hipLaunchKernelGGL(prep_w, dim3(898), dim3(256), 0, stream,
                       Wv, Wso, Waw, Wo, bso, baw, WvT, WsoawT, WoT, bias384);

    hipLaunchKernelGGL(gemm_dual, dim3(2, kMT), dim3(256), 0, stream,
                       value, (const __hip_bfloat16*)WvT, bv, v_b,
                       query, (const __hip_bfloat16*)WsoawT, bias384,
                       (unsigned short*)soaw);

    hipLaunchKernelGGL(msda_sample, dim3(kM), dim3(128), 0, stream,
                       (const __hip_bfloat16*)v_b, soaw, rp, (__hip_bfloat16*)mid_b);

    hipLaunchKernelGGL(gemm_final, dim3(1, kMT), dim3(256), 0, stream,
                       mid_b, (const __hip_bfloat16*)WoT, bo, query, (float*)d_out);
}

// Round 2
// 303.214 us; speedup vs baseline: 1.0750x; 1.0750x over previous
//
#include <hip/hip_runtime.h>
#include <hip/hip_bf16.h>
#include <math.h>

constexpr int kBS = 2;
constexpr int kNQ = 20197;
constexpr int kNV = 20197;
constexpr int kM  = kBS * kNQ;   // 40394
constexpr int kMT = 632;         // 64-row m-tiles (40448 rows incl. slack)
constexpr int kMpad = kMT * 64;  // 40448

__constant__ int cLH[4] = {100, 50, 25, 13};
__constant__ int cLW[4] = {152, 76, 38, 19};
__constant__ int cLS[4] = {0, 15200, 19000, 19950};

typedef __bf16 bf16x8 __attribute__((ext_vector_type(8)));
typedef float  f32x4  __attribute__((ext_vector_type(4)));
typedef float  f32x2  __attribute__((ext_vector_type(2)));

__device__ __forceinline__ unsigned short f2bf(float x) {
    unsigned u = __float_as_uint(x);
    return (unsigned short)((u + 0x7fffu + ((u >> 16) & 1u)) >> 16);
}
__device__ __forceinline__ unsigned pack2(float a, float b) {
    return (unsigned)f2bf(a) | ((unsigned)f2bf(b) << 16);
}
__device__ __forceinline__ float bflo(unsigned u) { return __uint_as_float(u << 16); }
__device__ __forceinline__ float bfhi(unsigned u) { return __uint_as_float(u & 0xffff0000u); }
__device__ __forceinline__ void gload_lds16(const void* g, void* s) {
    __builtin_amdgcn_global_load_lds(
        (const __attribute__((address_space(1))) void*)g,
        (__attribute__((address_space(3))) void*)s, 16, 0, 0);
}

// ---------------------------------------------------------------------------
// prep_w: weight transposes (fp32 KxN -> bf16 NxK) + fused bias384.
// Coalesced READS, scattered 2B writes (fire-and-forget).
// ---------------------------------------------------------------------------
__global__ __launch_bounds__(256) void prep_w(
    const float* __restrict__ Wv, const float* __restrict__ Wso,
    const float* __restrict__ Waw, const float* __restrict__ Wo,
    const float* __restrict__ bso, const float* __restrict__ baw,
    unsigned short* __restrict__ WvT, unsigned short* __restrict__ WsoawT,
    unsigned short* __restrict__ WoT, float* __restrict__ bias384)
{
    int k = blockIdx.x * 256 + threadIdx.x;
    if (k < 65536) { int kk = k >> 8, n = k & 255; WvT[n * 256 + kk] = f2bf(Wv[k]); return; }
    k -= 65536;
    if (k < 65536) { int kk = k >> 8, n = k & 255; WsoawT[n * 256 + kk] = f2bf(Wso[k]); return; }
    k -= 65536;
    if (k < 32768) { int kk = k >> 7, n = k & 127; WsoawT[(256 + n) * 256 + kk] = f2bf(Waw[k]); return; }
    k -= 32768;
    if (k < 65536) { int kk = k >> 8, n = k & 255; WoT[n * 256 + kk] = f2bf(Wo[k]); return; }
    k -= 65536;
    if (k < 384) bias384[k] = (k < 256) ? bso[k] : baw[k - 256];
}

// ---------------------------------------------------------------------------
// Panel GEMM core: C[64, N] = A_tile[64, 256] @ BT[N, 256]^T + bias (+res).
// r0-proven structure: A tile staged ONCE (pitch 264, conflict-free), B via
// double-buffered 8KB panels (global_load_lds) with __syncthreads per chunk,
// occupancy 3 blocks/CU. NEW: B panels XOR-swizzled (pre-swizzled DMA source
// + matching swizzled ds_read slot) -> 8-lane cycle groups hit all 8 bank
// groups (was 4-way conflict). 256 thr, 4 waves (2x2 over 32x64 outputs),
// mfma 16x16x32, acc 2x4.
// ---------------------------------------------------------------------------
template<int AFP32, int CFP32>
__device__ __forceinline__ void gemm_core(
    const void* __restrict__ Av, const __hip_bfloat16* __restrict__ BT,
    const float* __restrict__ bias, const float* __restrict__ res,
    int N, int NT, void* __restrict__ Cv, int m0)
{
    __shared__ __hip_bfloat16 As[64 * 264];      // ~33 KB, pitch 264
    __shared__ __hip_bfloat16 Bs[2][128 * 32];   // 2 x 8 KB

    const int t = threadIdx.x;
    const int wave = t >> 6, lane = t & 63;
    const int quad = lane >> 4, l16 = lane & 15;
    const int mw = (wave & 1) * 32, nw = (wave >> 1) * 64;

    // B panel: 512 slots of 16B. Physical slot s = row*4 + qp holds logical
    // k-block ql = qp ^ ((row>>1)&3)  (involution; same XOR on read side).
    auto issueB = [&](int nti, int kc, int buf) {
        #pragma unroll
        for (int j = 0; j < 2; ++j) {
            int s = j * 256 + t;
            int row = s >> 2;
            int ql = (s & 3) ^ ((row >> 1) & 3);
            gload_lds16((const char*)BT + (size_t)(nti * 128 + row) * 512
                            + kc * 64 + ql * 16,
                        (char*)&Bs[buf][0] + s * 16);
        }
    };

    issueB(0, 0, 0);   // first B panel in flight during A staging

    if (AFP32) {
        const float* af = (const float*)Av;
        #pragma unroll
        for (int p = 0; p < 16; ++p) {
            int idx = p * 256 + t;
            int row = idx >> 6, col4 = idx & 63;
            float4 f = make_float4(0.f, 0.f, 0.f, 0.f);
            if (m0 + row < kM)
                f = *(const float4*)(af + (size_t)(m0 + row) * 256 + col4 * 4);
            uint2 u = make_uint2(pack2(f.x, f.y), pack2(f.z, f.w));
            *(uint2*)(void*)&As[row * 264 + col4 * 4] = u;
        }
    } else {
        const unsigned short* ab = (const unsigned short*)Av;  // kMpad rows: no guard
        #pragma unroll
        for (int p = 0; p < 8; ++p) {
            int idx = p * 256 + t;
            int row = idx >> 5, ch = idx & 31;
            uint4 u = *(const uint4*)(ab + (size_t)(m0 + row) * 256 + ch * 8);
            *(uint4*)(void*)&As[row * 264 + ch * 8] = u;
        }
    }

    for (int nti = 0; nti < NT; ++nti) {
        f32x4 acc[2][4] = {};
        for (int kc = 0; kc < 8; ++kc) {
            __syncthreads();     // drains current B panel (+ A stage on iter 0)
            if (kc < 7)             issueB(nti, kc + 1, (kc + 1) & 1);
            else if (nti + 1 < NT)  issueB(nti + 1, 0, 0);
            bf16x8 afr[2], bfr[4];
            #pragma unroll
            for (int mt = 0; mt < 2; ++mt)
                afr[mt] = *(const bf16x8*)(const void*)
                    &As[(mw + mt * 16 + l16) * 264 + kc * 32 + quad * 8];
            #pragma unroll
            for (int nt = 0; nt < 4; ++nt) {
                int r = nw + nt * 16 + l16;
                int qp = quad ^ ((r >> 1) & 3);          // swizzled slot
                bfr[nt] = *(const bf16x8*)(const void*)
                    &Bs[kc & 1][r * 32 + qp * 8];
            }
            #pragma unroll
            for (int mt = 0; mt < 2; ++mt)
                #pragma unroll
                for (int nt = 0; nt < 4; ++nt)
                    acc[mt][nt] = __builtin_amdgcn_mfma_f32_16x16x32_bf16(
                        afr[mt], bfr[nt], acc[mt][nt], 0, 0, 0);
        }
        // epilogue for this n-tile (C/D: col=lane&15, row=quad*4+reg)
        const int n0g = nti * 128;
        #pragma unroll
        for (int nt = 0; nt < 4; ++nt) {
            int col = n0g + nw + nt * 16 + l16;
            float bvv = bias[col];
            #pragma unroll
            for (int mt = 0; mt < 2; ++mt) {
                #pragma unroll
                for (int i = 0; i < 4; ++i) {
                    int row = m0 + mw + mt * 16 + quad * 4 + i;
                    if (row < kM) {
                        float val = acc[mt][nt][i] + bvv;
                        if (CFP32)
                            ((float*)Cv)[(size_t)row * N + col] =
                                val + res[(size_t)row * N + col];
                        else
                            ((unsigned short*)Cv)[(size_t)row * N + col] = f2bf(val);
                    }
                }
            }
        }
    }
}

// bx=0: v_b = value @ WvT^T + bv; bx=1: soaw = query @ WsoawT^T + bias384
__global__ __launch_bounds__(256, 3) void gemm_dual(
    const float* __restrict__ value, const __hip_bfloat16* __restrict__ WvT,
    const float* __restrict__ bv, unsigned short* __restrict__ v_b,
    const float* __restrict__ query, const __hip_bfloat16* __restrict__ WsoawT,
    const float* __restrict__ b384, unsigned short* __restrict__ soaw)
{
    const int m0 = blockIdx.y * 64;
    const float* A; const __hip_bfloat16* BT; const float* bias;
    unsigned short* C; int N, NT;
    if (blockIdx.x == 0) { A = value; BT = WvT;    bias = bv;   C = v_b;  N = 256; NT = 2; }
    else                 { A = query; BT = WsoawT; bias = b384; C = soaw; N = 384; NT = 3; }
    gemm_core<1, 0>(A, BT, bias, nullptr, N, NT, C, m0);
}

// out = mid_b(bf16) @ WoT^T + bo + query (fp32 out)
__global__ __launch_bounds__(256, 3) void gemm_final(
    const unsigned short* __restrict__ mid_b, const __hip_bfloat16* __restrict__ WoT,
    const float* __restrict__ bo, const float* __restrict__ query,
    float* __restrict__ out)
{
    gemm_core<0, 1>(mid_b, WoT, bo, query, 256, 2, out, blockIdx.y * 64);
}

// ---------------------------------------------------------------------------
// Sampler (r1-proven, 89 us): 1 block (128 thr) per query. Phase 1 stores
// (byte_off, weight) interleaved as int2 -> single ds_read_b64 in phase 2.
// Phase 2: uniform-base saddr loads (1 v_add), packed f32x2 FMA.
// ---------------------------------------------------------------------------
__global__ __launch_bounds__(128) void msda_sample(
    const __hip_bfloat16* __restrict__ v,     // (BS*NV, 256) bf16
    const __hip_bfloat16* __restrict__ soaw,  // (M, 384) bf16: so | logits
    const float* __restrict__ rp,             // (M, 4, 2)
    __hip_bfloat16* __restrict__ mid)         // (kMpad, 256) bf16
{
    const int bq = blockIdx.x;
    const int b  = bq >= kNQ;
    const int t  = threadIdx.x;

    __shared__ int2 sP[128 * 5];   // 5120 B: (byte_off, weight) x4 + pad

    {   // phase 1
        const int h = t >> 4, lp = t & 15, l = lp >> 2;
        unsigned sopk = *(const unsigned*)(const void*)(soaw + (size_t)bq * 384 + 2 * t);
        float logit = bflo((unsigned)*(const unsigned short*)(const void*)
                           (soaw + (size_t)bq * 384 + 256 + t));
        float2 rr = *(const float2*)(rp + (size_t)bq * 8 + l * 2);
        float sx = bflo(sopk), sy = bfhi(sopk);

        float mx = logit;
        #pragma unroll
        for (int s = 8; s >= 1; s >>= 1) mx = fmaxf(mx, __shfl_xor(mx, s, 16));
        float e = __expf(logit - mx);
        float sum = e;
        #pragma unroll
        for (int s = 8; s >= 1; s >>= 1) sum += __shfl_xor(sum, s, 16);
        float w = e / sum;

        const int ww = cLW[l], hh = cLH[l];
        const float fw = (float)ww, fh = (float)hh;
        float x = rr.x * fw + sx - 0.5f;
        float y = rr.y * fh + sy - 0.5f;
        float xf = floorf(x), yf = floorf(y);
        int x0 = (int)xf, y0 = (int)yf;
        float wx1 = x - xf, wx0 = 1.f - wx1;
        float wy1 = y - yf, wy0 = 1.f - wy1;
        bool vx0 = (x0 >= 0) & (x0 < ww);
        bool vx1 = (x0 >= -1) & (x0 + 1 < ww);
        bool vy0 = (y0 >= 0) & (y0 < hh);
        bool vy1 = (y0 >= -1) & (y0 + 1 < hh);
        int cx0 = min(max(x0, 0), ww - 1);
        int cx1 = min(max(x0 + 1, 0), ww - 1);
        int cy0 = min(max(y0, 0), hh - 1);
        int cy1 = min(max(y0 + 1, 0), hh - 1);
        const int base2 = cLS[l] * 512 + h * 64;             // BYTE offsets
        sP[t * 5 + 0] = make_int2(base2 + (cy0 * ww + cx0) * 512,
                                  __float_as_int((vx0 & vy0) ? w * wx0 * wy0 : 0.f));
        sP[t * 5 + 1] = make_int2(base2 + (cy0 * ww + cx1) * 512,
                                  __float_as_int((vx1 & vy0) ? w * wx1 * wy0 : 0.f));
        sP[t * 5 + 2] = make_int2(base2 + (cy1 * ww + cx0) * 512,
                                  __float_as_int((vx0 & vy1) ? w * wx0 * wy1 : 0.f));
        sP[t * 5 + 3] = make_int2(base2 + (cy1 * ww + cx1) * 512,
                                  __float_as_int((vx1 & vy1) ? w * wx1 * wy1 : 0.f));
    }
    __syncthreads();

    // phase 2
    const int h = t >> 4, c = (t & 15) * 2;
    const char* vb = (const char*)v + (size_t)b * ((size_t)kNV * 512);  // uniform base
    const unsigned cb = (unsigned)(c * 2);
    f32x2 acc = {0.f, 0.f};
    const int p0 = h * 16;
    #pragma unroll 8
    for (int pp = 0; pp < 16; ++pp) {
        const int idx = (p0 + pp) * 5;
        #pragma unroll
        for (int k2 = 0; k2 < 4; ++k2) {
            int2 pw = sP[idx + k2];
            float wgt = __int_as_float(pw.y);
            unsigned u = *(const unsigned*)(const void*)(vb + ((unsigned)pw.x + cb));
            f32x2 xy; xy.x = bflo(u); xy.y = bfhi(u);
            f32x2 w2; w2.x = wgt; w2.y = wgt;
            acc = xy * w2 + acc;          // ffp-contract -> v_pk_fma_f32
        }
    }
    *(unsigned*)(void*)(mid + (size_t)bq * 256 + h * 32 + c) = pack2(acc.x, acc.y);
}

// ---------------------------------------------------------------------------
extern "C" void kernel_launch(void* const* d_in, const int* in_sizes, int n_in,
                              void* d_out, int out_size, void* d_ws, size_t ws_size,
                              hipStream_t stream)
{
    const float* query = (const float*)d_in[0];
    const float* value = (const float*)d_in[1];
    const float* rp    = (const float*)d_in[2];
    const float* Wv  = (const float*)d_in[5];
    const float* bv  = (const float*)d_in[6];
    const float* Wso = (const float*)d_in[7];
    const float* bso = (const float*)d_in[8];
    const float* Waw = (const float*)d_in[9];
    const float* baw = (const float*)d_in[10];
    const float* Wo  = (const float*)d_in[11];
    const float* bo  = (const float*)d_in[12];

    // d_out overlay: v_b bf16 (kM*512 B) in first half; dead before the
    // final GEMM rewrites all of d_out.
    unsigned short* v_b = (unsigned short*)d_out;

    // ws: soaw bf16 (kM*384) | mid_b bf16 (kMpad*256) | WvT | WsoawT | WoT | bias384
    char* p = (char*)d_ws;
    __hip_bfloat16* soaw  = (__hip_bfloat16*)p;  p += (size_t)kM * 384 * 2;
    unsigned short* mid_b = (unsigned short*)p;  p += (size_t)kMpad * 256 * 2;
    unsigned short* WvT    = (unsigned short*)p; p += 256 * 256 * 2;
    unsigned short* WsoawT = (unsigned short*)p; p += 384 * 256 * 2;
    unsigned short* WoT    = (unsigned short*)p; p += 256 * 256 * 2;
    float* bias384         = (float*)p;

    hipLaunchKernelGGL(prep_w, dim3(898), dim3(256), 0, stream,
                       Wv, Wso, Waw, Wo, bso, baw, WvT, WsoawT, WoT, bias384);

    hipLaunchKernelGGL(gemm_dual, dim3(2, kMT), dim3(256), 0, stream,
                       value, (const __hip_bfloat16*)WvT, bv, v_b,
                       query, (const __hip_bfloat16*)WsoawT, bias384,
                       (unsigned short*)soaw);

    hipLaunchKernelGGL(msda_sample, dim3(kM), dim3(128), 0, stream,
                       (const __hip_bfloat16*)v_b, soaw, rp, (__hip_bfloat16*)mid_b);

    hipLaunchKernelGGL(gemm_final, dim3(1, kMT), dim3(256), 0, stream,
                       mid_b, (const __hip_bfloat16*)WoT, bo, query, (float*)d_out);
}

// Round 6
// 287.138 us; speedup vs baseline: 1.1352x; 1.0560x over previous
//
#include <hip/hip_runtime.h>
#include <hip/hip_bf16.h>
#include <math.h>

constexpr int kBS = 2;
constexpr int kNQ = 20197;
constexpr int kNV = 20197;
constexpr int kM  = kBS * kNQ;   // 40394
constexpr int kMT = 632;         // 64-row m-tiles (40448 rows incl. slack)
constexpr int kMpad = kMT * 64;  // 40448

__constant__ int cLH[4] = {100, 50, 25, 13};
__constant__ int cLW[4] = {152, 76, 38, 19};
__constant__ int cLS[4] = {0, 15200, 19000, 19950};

typedef __bf16 bf16x8 __attribute__((ext_vector_type(8)));
typedef float  f32x4  __attribute__((ext_vector_type(4)));
typedef float  f32x2  __attribute__((ext_vector_type(2)));

__device__ __forceinline__ unsigned short f2bf(float x) {
    unsigned u = __float_as_uint(x);
    return (unsigned short)((u + 0x7fffu + ((u >> 16) & 1u)) >> 16);
}
__device__ __forceinline__ unsigned pack2(float a, float b) {
    return (unsigned)f2bf(a) | ((unsigned)f2bf(b) << 16);
}
__device__ __forceinline__ float bflo(unsigned u) { return __uint_as_float(u << 16); }
__device__ __forceinline__ float bfhi(unsigned u) { return __uint_as_float(u & 0xffff0000u); }
__device__ __forceinline__ void gload_lds16(const void* g, void* s) {
    __builtin_amdgcn_global_load_lds(
        (const __attribute__((address_space(1))) void*)g,
        (__attribute__((address_space(3))) void*)s, 16, 0, 0);
}

// ---------------------------------------------------------------------------
// prep_w: weight transposes (fp32 KxN -> bf16 NxK) + fused bias384.
// Coalesced READS, scattered 2B writes (fire-and-forget).
// ---------------------------------------------------------------------------
__global__ __launch_bounds__(256) void prep_w(
    const float* __restrict__ Wv, const float* __restrict__ Wso,
    const float* __restrict__ Waw, const float* __restrict__ Wo,
    const float* __restrict__ bso, const float* __restrict__ baw,
    unsigned short* __restrict__ WvT, unsigned short* __restrict__ WsoawT,
    unsigned short* __restrict__ WoT, float* __restrict__ bias384)
{
    int k = blockIdx.x * 256 + threadIdx.x;
    if (k < 65536) { int kk = k >> 8, n = k & 255; WvT[n * 256 + kk] = f2bf(Wv[k]); return; }
    k -= 65536;
    if (k < 65536) { int kk = k >> 8, n = k & 255; WsoawT[n * 256 + kk] = f2bf(Wso[k]); return; }
    k -= 65536;
    if (k < 32768) { int kk = k >> 7, n = k & 127; WsoawT[(256 + n) * 256 + kk] = f2bf(Waw[k]); return; }
    k -= 32768;
    if (k < 65536) { int kk = k >> 8, n = k & 255; WoT[n * 256 + kk] = f2bf(Wo[k]); return; }
    k -= 65536;
    if (k < 384) bias384[k] = (k < 256) ? bso[k] : baw[k - 256];
}

// ---------------------------------------------------------------------------
// Panel GEMM core: C[64, N] = A_tile[64, 256] @ BT[N, 256]^T + bias (+res).
// Sync structure = r2-PROVEN (303 us, passed): __syncthreads per chunk,
// double-buffered 8KB B panels via global_load_lds (lane-linear dest,
// XOR-swizzled global source + matching swizzled ds_read slot), pitch-264
// As via explicit ds_writes, 3 blocks/CU.
// NEW vs r2: SWAPPED MFMA operands — mfma(bfr, afr) computes the transposed
// fragment, so each lane holds 4 CONSECUTIVE COLUMNS at a fixed row
// (D: row=n_local=quad*4+i, col=m_local=l16). Epilogue becomes one float4
// (fp32) / packed uint2 (bf16) store per (mt,nt) with float4 bias/residual
// loads: 32 scalar stores -> 2-8 vector stores per n-tile. K=256 has only
// 8 chunks/n-tile, so epilogue overhead is a large fixed fraction here.
// ---------------------------------------------------------------------------
template<int AFP32, int CFP32>
__device__ __forceinline__ void gemm_core(
    const void* __restrict__ Av, const __hip_bfloat16* __restrict__ BT,
    const float* __restrict__ bias, const float* __restrict__ res,
    int N, int NT, void* __restrict__ Cv, int m0)
{
    __shared__ __hip_bfloat16 As[64 * 264];      // ~33 KB, pitch 264
    __shared__ __hip_bfloat16 Bs[2][128 * 32];   // 2 x 8 KB

    const int t = threadIdx.x;
    const int wave = t >> 6, lane = t & 63;
    const int quad = lane >> 4, l16 = lane & 15;
    const int mw = (wave & 1) * 32, nw = (wave >> 1) * 64;

    // B panel: 512 slots of 16B. Physical slot s = row*4 + qp holds logical
    // k-block ql = qp ^ ((row>>1)&3)  (involution; same XOR on read side).
    auto issueB = [&](int nti, int kc, int buf) {
        #pragma unroll
        for (int j = 0; j < 2; ++j) {
            int s = j * 256 + t;
            int row = s >> 2;
            int ql = (s & 3) ^ ((row >> 1) & 3);
            gload_lds16((const char*)BT + (size_t)(nti * 128 + row) * 512
                            + kc * 64 + ql * 16,
                        (char*)&Bs[buf][0] + s * 16);
        }
    };

    issueB(0, 0, 0);   // first B panel in flight during A staging

    if (AFP32) {
        const float* af = (const float*)Av;
        #pragma unroll
        for (int p = 0; p < 16; ++p) {
            int idx = p * 256 + t;
            int row = idx >> 6, col4 = idx & 63;
            float4 f = make_float4(0.f, 0.f, 0.f, 0.f);
            if (m0 + row < kM)
                f = *(const float4*)(af + (size_t)(m0 + row) * 256 + col4 * 4);
            uint2 u = make_uint2(pack2(f.x, f.y), pack2(f.z, f.w));
            *(uint2*)(void*)&As[row * 264 + col4 * 4] = u;
        }
    } else {
        const unsigned short* ab = (const unsigned short*)Av;  // kMpad rows: no guard
        #pragma unroll
        for (int p = 0; p < 8; ++p) {
            int idx = p * 256 + t;
            int row = idx >> 5, ch = idx & 31;
            uint4 u = *(const uint4*)(ab + (size_t)(m0 + row) * 256 + ch * 8);
            *(uint4*)(void*)&As[row * 264 + ch * 8] = u;
        }
    }

    for (int nti = 0; nti < NT; ++nti) {
        f32x4 acc[2][4] = {};
        for (int kc = 0; kc < 8; ++kc) {
            __syncthreads();     // drains current B panel (+ A stage on iter 0)
            if (kc < 7)             issueB(nti, kc + 1, (kc + 1) & 1);
            else if (nti + 1 < NT)  issueB(nti + 1, 0, 0);
            bf16x8 afr[2], bfr[4];
            #pragma unroll
            for (int mt = 0; mt < 2; ++mt)
                afr[mt] = *(const bf16x8*)(const void*)
                    &As[(mw + mt * 16 + l16) * 264 + kc * 32 + quad * 8];
            #pragma unroll
            for (int nt = 0; nt < 4; ++nt) {
                int r = nw + nt * 16 + l16;
                int qp = quad ^ ((r >> 1) & 3);          // swizzled slot
                bfr[nt] = *(const bf16x8*)(const void*)
                    &Bs[kc & 1][r * 32 + qp * 8];
            }
            // SWAPPED operands: D row index = B rows (n), col index = A rows (m)
            #pragma unroll
            for (int mt = 0; mt < 2; ++mt)
                #pragma unroll
                for (int nt = 0; nt < 4; ++nt)
                    acc[mt][nt] = __builtin_amdgcn_mfma_f32_16x16x32_bf16(
                        bfr[nt], afr[mt], acc[mt][nt], 0, 0, 0);
        }
        // epilogue: lane holds cols n0..n0+3 (n0 = ...+quad*4) at row ...+l16
        const int n0g = nti * 128;
        #pragma unroll
        for (int nt = 0; nt < 4; ++nt) {
            int n0 = n0g + nw + nt * 16 + quad * 4;
            float4 b4 = *(const float4*)&bias[n0];
            #pragma unroll
            for (int mt = 0; mt < 2; ++mt) {
                int row = m0 + mw + mt * 16 + l16;
                if (row < kM) {
                    f32x4 a = acc[mt][nt];
                    if (CFP32) {
                        float4 r4 = *(const float4*)(res + (size_t)row * N + n0);
                        float4 o;
                        o.x = a[0] + b4.x + r4.x;
                        o.y = a[1] + b4.y + r4.y;
                        o.z = a[2] + b4.z + r4.z;
                        o.w = a[3] + b4.w + r4.w;
                        *(float4*)((float*)Cv + (size_t)row * N + n0) = o;
                    } else {
                        uint2 u = make_uint2(pack2(a[0] + b4.x, a[1] + b4.y),
                                             pack2(a[2] + b4.z, a[3] + b4.w));
                        *(uint2*)((unsigned short*)Cv + (size_t)row * N + n0) = u;
                    }
                }
            }
        }
    }
}

// bx=0: v_b = value @ WvT^T + bv; bx=1: soaw = query @ WsoawT^T + bias384
__global__ __launch_bounds__(256, 3) void gemm_dual(
    const float* __restrict__ value, const __hip_bfloat16* __restrict__ WvT,
    const float* __restrict__ bv, unsigned short* __restrict__ v_b,
    const float* __restrict__ query, const __hip_bfloat16* __restrict__ WsoawT,
    const float* __restrict__ b384, unsigned short* __restrict__ soaw)
{
    const int m0 = blockIdx.y * 64;
    const float* A; const __hip_bfloat16* BT; const float* bias;
    unsigned short* C; int N, NT;
    if (blockIdx.x == 0) { A = value; BT = WvT;    bias = bv;   C = v_b;  N = 256; NT = 2; }
    else                 { A = query; BT = WsoawT; bias = b384; C = soaw; N = 384; NT = 3; }
    gemm_core<1, 0>(A, BT, bias, nullptr, N, NT, C, m0);
}

// out = mid_b(bf16) @ WoT^T + bo + query (fp32 out)
__global__ __launch_bounds__(256, 3) void gemm_final(
    const unsigned short* __restrict__ mid_b, const __hip_bfloat16* __restrict__ WoT,
    const float* __restrict__ bo, const float* __restrict__ query,
    float* __restrict__ out)
{
    gemm_core<0, 1>(mid_b, WoT, bo, query, 256, 2, out, blockIdx.y * 64);
}

// ---------------------------------------------------------------------------
// Sampler (r1/r2-proven, ~90 us): 1 block (128 thr) per query. Phase 1 stores
// (byte_off, weight) interleaved as int2 -> single ds_read_b64 in phase 2.
// Phase 2: uniform-base saddr loads (1 v_add), packed f32x2 FMA.
// ---------------------------------------------------------------------------
__global__ __launch_bounds__(128) void msda_sample(
    const __hip_bfloat16* __restrict__ v,     // (BS*NV, 256) bf16
    const __hip_bfloat16* __restrict__ soaw,  // (M, 384) bf16: so | logits
    const float* __restrict__ rp,             // (M, 4, 2)
    __hip_bfloat16* __restrict__ mid)         // (kMpad, 256) bf16
{
    const int bq = blockIdx.x;
    const int b  = bq >= kNQ;
    const int t  = threadIdx.x;

    __shared__ int2 sP[128 * 5];   // 5120 B: (byte_off, weight) x4 + pad

    {   // phase 1
        const int h = t >> 4, lp = t & 15, l = lp >> 2;
        unsigned sopk = *(const unsigned*)(const void*)(soaw + (size_t)bq * 384 + 2 * t);
        float logit = bflo((unsigned)*(const unsigned short*)(const void*)
                           (soaw + (size_t)bq * 384 + 256 + t));
        float2 rr = *(const float2*)(rp + (size_t)bq * 8 + l * 2);
        float sx = bflo(sopk), sy = bfhi(sopk);

        float mx = logit;
        #pragma unroll
        for (int s = 8; s >= 1; s >>= 1) mx = fmaxf(mx, __shfl_xor(mx, s, 16));
        float e = __expf(logit - mx);
        float sum = e;
        #pragma unroll
        for (int s = 8; s >= 1; s >>= 1) sum += __shfl_xor(sum, s, 16);
        float w = e / sum;

        const int ww = cLW[l], hh = cLH[l];
        const float fw = (float)ww, fh = (float)hh;
        float x = rr.x * fw + sx - 0.5f;
        float y = rr.y * fh + sy - 0.5f;
        float xf = floorf(x), yf = floorf(y);
        int x0 = (int)xf, y0 = (int)yf;
        float wx1 = x - xf, wx0 = 1.f - wx1;
        float wy1 = y - yf, wy0 = 1.f - wy1;
        bool vx0 = (x0 >= 0) & (x0 < ww);
        bool vx1 = (x0 >= -1) & (x0 + 1 < ww);
        bool vy0 = (y0 >= 0) & (y0 < hh);
        bool vy1 = (y0 >= -1) & (y0 + 1 < hh);
        int cx0 = min(max(x0, 0), ww - 1);
        int cx1 = min(max(x0 + 1, 0), ww - 1);
        int cy0 = min(max(y0, 0), hh - 1);
        int cy1 = min(max(y0 + 1, 0), hh - 1);
        const int base2 = cLS[l] * 512 + h * 64;             // BYTE offsets
        sP[t * 5 + 0] = make_int2(base2 + (cy0 * ww + cx0) * 512,
                                  __float_as_int((vx0 & vy0) ? w * wx0 * wy0 : 0.f));
        sP[t * 5 + 1] = make_int2(base2 + (cy0 * ww + cx1) * 512,
                                  __float_as_int((vx1 & vy0) ? w * wx1 * wy0 : 0.f));
        sP[t * 5 + 2] = make_int2(base2 + (cy1 * ww + cx0) * 512,
                                  __float_as_int((vx0 & vy1) ? w * wx0 * wy1 : 0.f));
        sP[t * 5 + 3] = make_int2(base2 + (cy1 * ww + cx1) * 512,
                                  __float_as_int((vx1 & vy1) ? w * wx1 * wy1 : 0.f));
    }
    __syncthreads();

    // phase 2
    const int h = t >> 4, c = (t & 15) * 2;
    const char* vb = (const char*)v + (size_t)b * ((size_t)kNV * 512);  // uniform base
    const unsigned cb = (unsigned)(c * 2);
    f32x2 acc = {0.f, 0.f};
    const int p0 = h * 16;
    #pragma unroll 8
    for (int pp = 0; pp < 16; ++pp) {
        const int idx = (p0 + pp) * 5;
        #pragma unroll
        for (int k2 = 0; k2 < 4; ++k2) {
            int2 pw = sP[idx + k2];
            float wgt = __int_as_float(pw.y);
            unsigned u = *(const unsigned*)(const void*)(vb + ((unsigned)pw.x + cb));
            f32x2 xy; xy.x = bflo(u); xy.y = bfhi(u);
            f32x2 w2; w2.x = wgt; w2.y = wgt;
            acc = xy * w2 + acc;          // ffp-contract -> v_pk_fma_f32
        }
    }
    *(unsigned*)(void*)(mid + (size_t)bq * 256 + h * 32 + c) = pack2(acc.x, acc.y);
}

// ---------------------------------------------------------------------------
extern "C" void kernel_launch(void* const* d_in, const int* in_sizes, int n_in,
                              void* d_out, int out_size, void* d_ws, size_t ws_size,
                              hipStream_t stream)
{
    const float* query = (const float*)d_in[0];
    const float* value = (const float*)d_in[1];
    const float* rp    = (const float*)d_in[2];
    const float* Wv  = (const float*)d_in[5];
    const float* bv  = (const float*)d_in[6];
    const float* Wso = (const float*)d_in[7];
    const float* bso = (const float*)d_in[8];
    const float* Waw = (const float*)d_in[9];
    const float* baw = (const float*)d_in[10];
    const float* Wo  = (const float*)d_in[11];
    const float* bo  = (const float*)d_in[12];

    // d_out overlay: v_b bf16 (kM*512 B) in first half; dead before the
    // final GEMM rewrites all of d_out.
    unsigned short* v_b = (unsigned short*)d_out;

    // ws: soaw bf16 (kM*384) | mid_b bf16 (kMpad*256) | WvT | WsoawT | WoT | bias384
    char* p = (char*)d_ws;
    __hip_bfloat16* soaw  = (__hip_bfloat16*)p;  p += (size_t)kM * 384 * 2;
    unsigned short* mid_b = (unsigned short*)p;  p += (size_t)kMpad * 256 * 2;
    unsigned short* WvT    = (unsigned short*)p; p += 256 * 256 * 2;
    unsigned short* WsoawT = (unsigned short*)p; p += 384 * 256 * 2;
    unsigned short* WoT    = (unsigned short*)p; p += 256 * 256 * 2;
    float* bias384         = (float*)p;

    hipLaunchKernelGGL(prep_w, dim3(898), dim3(256), 0, stream,
                       Wv, Wso, Waw, Wo, bso, baw, WvT, WsoawT, WoT, bias384);

    hipLaunchKernelGGL(gemm_dual, dim3(2, kMT), dim3(256), 0, stream,
                       value, (const __hip_bfloat16*)WvT, bv, v_b,
                       query, (const __hip_bfloat16*)WsoawT, bias384,
                       (unsigned short*)soaw);

    hipLaunchKernelGGL(msda_sample, dim3(kM), dim3(128), 0, stream,
                       (const __hip_bfloat16*)v_b, soaw, rp, (__hip_bfloat16*)mid_b);

    hipLaunchKernelGGL(gemm_final, dim3(1, kMT), dim3(256), 0, stream,
                       mid_b, (const __hip_bfloat16*)WoT, bo, query, (float*)d_out);
}